// Round 11
// baseline (1368.785 us; speedup 1.0000x reference)
//
#include <hip/hip_runtime.h>
#include <math.h>

#define TT 1024
#define U1 128
#define U2 32
#define NCOL 480   // 384 rk1 gate-cols + 96 k2 cols (both dot against h1)
#define NCP 240    // long col-pairs
#define NUQ 4      // u-quarters

typedef float f2 __attribute__((ext_vector_type(2)));

// v_pk_fma_f32: D = S0*S1 + S2 on 2xf32 packed (VGPR pairs).
// PK_LO: both halves multiply by h.x ; PK_HI: both halves multiply by h.y
// (verified bit-exact in R7/R10: absmax 1.49e-8 unchanged)
#define PK_LO(acc, w, h) asm("v_pk_fma_f32 %0, %1, %2, %0 op_sel:[0,0,0] op_sel_hi:[1,0,1]" \
                             : "+v"(acc) : "v"(w), "v"(h))
#define PK_HI(acc, w, h) asm("v_pk_fma_f32 %0, %1, %2, %0 op_sel:[0,1,0] op_sel_hi:[1,1,1]" \
                             : "+v"(acc) : "v"(w), "v"(h))

__device__ __forceinline__ float fast_tanh(float v) {
    float e = __expf(2.f * v);      // v>>0: e=inf -> 1; v<<0: e=0 -> -1 (NaN-free)
    return 1.f - 2.f / (e + 1.f);
}
__device__ __forceinline__ float fast_sig(float v) {
    return 1.f / (1.f + __expf(-v));
}

// TWO INDEPENDENT BLOCKS PER CU. R0..R10 post-mortems: step time is pinned at
// ~2670 cyc/CU regardless of issue (pk null), barriers (1v2 null), waves
// (8v16 null) -> the binder is ONE serial chain per CU (LDS latency + barrier
// skew + update tail). Fix: 512 blocks x 1024 threads, 1 batch/block,
// __launch_bounds__(1024,2) -> 2 co-resident blocks/CU (32 waves): block A's
// serial shadow fills with block B's dot work. Per-thread state is R10's
// minus one batch (proven VGPR=64 honest fit; R1's spill was the 64-cap vs
// 128-float footprint, not the concept).
// Dot: thread owns col-pair {2p,2p+1} x 32-u range; 8 broadcast b128 reads,
//   32 pk_fma. t<960: [rk1|k2] vs h1 (uq=t/240). 960<=t<1008: rk2 vs h2.
// Update: t<128 GRU1 (h_old in reg); t 128..159 GRU2 lagged one step.
// 2 barriers/step.
__global__ __launch_bounds__(1024, 2)
void gru_stack_kernel(const float* __restrict__ x,   // [512,1024,1]
                      const float* __restrict__ k1,  // [1,384]
                      const float* __restrict__ rk1, // [128,384]
                      const float* __restrict__ b1,  // [2,384]
                      const float* __restrict__ k2,  // [128,96]
                      const float* __restrict__ rk2, // [32,96]
                      const float* __restrict__ b2,  // [2,96]
                      const float* __restrict__ wd,  // [32,1]
                      const float* __restrict__ bd,  // [1]
                      float* __restrict__ out)       // [512,1]
{
    __shared__ __align__(16) float h1s[U1];
    __shared__ __align__(16) float h2s[U2];
    __shared__ __align__(16) float part1[NUQ][NCOL];  // [uq][col]
    __shared__ __align__(16) float part2[96];         // rk2 partials
    __shared__ __align__(16) float xs[TT];            // staged x row

    const int t = threadIdx.x;
    const int b = blockIdx.x;

    if (t < U1) h1s[t] = 0.f;
    if (t < U2) h2s[t] = 0.f;
    if (t < TT) xs[t] = x[b * TT + t];                // coalesced x stage

    // ---------------- dot-role setup ----------------
    f2 w2[32];                          // 64 VGPRs: col-pair {c0,c0+1} x 32 u
    const float4* pb = nullptr;         // h source
    float2* pd = nullptr;               // partial dest
    const bool is_dot = (t < 1008);
    if (t < 960) {
        const int uq = t / NCP, p = t % NCP;
        const int c0 = 2 * p, ub = 32 * uq;
#pragma unroll
        for (int j = 0; j < 32; ++j) {
            const int u = ub + j;
            float vv[2];
#pragma unroll
            for (int r = 0; r < 2; ++r) {
                const int c = c0 + r;
                vv[r] = (c < 384) ? rk1[u * 384 + c] : k2[u * 96 + (c - 384)];
            }
            w2[j].x = vv[0]; w2[j].y = vv[1];
        }
        pb = (const float4*)&h1s[ub];
        pd = (float2*)&part1[uq][c0];
    } else if (t < 1008) {
        const int q2 = t - 960, c0 = 2 * q2;
#pragma unroll
        for (int j = 0; j < 32; ++j) {
            w2[j].x = rk2[j * 96 + c0 + 0];
            w2[j].y = rk2[j * 96 + c0 + 1];
        }
        pb = (const float4*)&h2s[0];
        pd = (float2*)&part2[c0];
    } else {
#pragma unroll
        for (int j = 0; j < 32; ++j) { w2[j].x = 0.f; w2[j].y = 0.f; }
    }

    // ---------------- update-role setup ----------------
    const int ju = t;                                  // t<128: GRU1 unit
    float k1z = 0, k1r = 0, k1h = 0, bz = 0, br = 0, bhx = 0, bhr = 0, h_old = 0;
    if (t < 128) {
        k1z = k1[ju]; k1r = k1[128 + ju]; k1h = k1[256 + ju];
        bz  = b1[ju]       + b1[384 + ju];
        br  = b1[128 + ju] + b1[384 + 128 + ju];
        bhx = b1[256 + ju];
        bhr = b1[384 + 256 + ju];
    }
    const int j2 = t - 128;                            // t 128..159: GRU2 unit
    float bz2 = 0, br2 = 0, bh2x = 0, bh2r = 0, h2_old = 0;
    if (t >= 128 && t < 160) {
        bz2  = b2[j2]      + b2[96 + j2];
        br2  = b2[32 + j2] + b2[96 + 32 + j2];
        bh2x = b2[64 + j2];
        bh2r = b2[96 + 64 + j2];
    }

    __syncthreads();  // B0: h init + x stage visible

    for (int i = 0; i <= TT; ++i) {
        if (is_dot) {
            f2 a = {0.f, 0.f};                       // cols {c0,c0+1}
#pragma unroll
            for (int k = 0; k < 8; ++k) {
                const float4 h4 = pb[k];             // h[4k..4k+3]
                const f2 hlo = {h4.x, h4.y}, hhi = {h4.z, h4.w};
                PK_LO(a, w2[4 * k],     hlo);        // u = 4k   (same FP order)
                PK_HI(a, w2[4 * k + 1], hlo);        // u = 4k+1
                PK_LO(a, w2[4 * k + 2], hhi);        // u = 4k+2
                PK_HI(a, w2[4 * k + 3], hhi);        // u = 4k+3
            }
            *pd = make_float2(a.x, a.y);
        }
        __syncthreads();  // B1: partials visible

        if (t < 128 && i < TT) {
            // GRU1 unit update: z/r = relu, hh = tanh (reset_after)
            const float xv = xs[i];
            float iz = part1[0][ju] + part1[1][ju]
                     + part1[2][ju] + part1[3][ju];
            float ir = part1[0][128 + ju] + part1[1][128 + ju]
                     + part1[2][128 + ju] + part1[3][128 + ju];
            float ih = part1[0][256 + ju] + part1[1][256 + ju]
                     + part1[2][256 + ju] + part1[3][256 + ju];
            float z  = fmaxf(fmaf(xv, k1z, bz) + iz, 0.f);
            float r  = fmaxf(fmaf(xv, k1r, br) + ir, 0.f);
            float hh = fast_tanh(fmaf(xv, k1h, bhx) + r * (ih + bhr));
            h_old = fmaf(z, h_old - hh, hh);
            h1s[ju] = h_old;
        } else if (t >= 128 && t < 160 && i >= 1) {
            // GRU2 unit update (one step behind): z/r = sigmoid, hh = relu
            float xz = part1[0][384 + j2] + part1[1][384 + j2]
                     + part1[2][384 + j2] + part1[3][384 + j2];
            float xr = part1[0][416 + j2] + part1[1][416 + j2]
                     + part1[2][416 + j2] + part1[3][416 + j2];
            float xh = part1[0][448 + j2] + part1[1][448 + j2]
                     + part1[2][448 + j2] + part1[3][448 + j2];
            float iz = part2[j2];
            float ir = part2[32 + j2];
            float ih = part2[64 + j2];
            float z  = fast_sig(xz + iz + bz2);
            float r  = fast_sig(xr + ir + br2);
            float hh = fmaxf(xh + bh2x + r * (ih + bh2r), 0.f);
            h2_old = fmaf(z, h2_old - hh, hh);
            h2s[j2] = h2_old;
        }
        __syncthreads();  // B2: h updated
    }

    // ---------------- dense head ----------------
    if (t < 32) {
        float p = h2s[t] * wd[t];
#pragma unroll
        for (int m = 16; m >= 1; m >>= 1) p += __shfl_xor(p, m, 64);
        if (t == 0) out[b] = p + bd[0];
    }
}

extern "C" void kernel_launch(void* const* d_in, const int* in_sizes, int n_in,
                              void* d_out, int out_size, void* d_ws, size_t ws_size,
                              hipStream_t stream) {
    const float* x   = (const float*)d_in[0];
    const float* k1  = (const float*)d_in[1];
    const float* rk1 = (const float*)d_in[2];
    const float* b1  = (const float*)d_in[3];
    const float* k2  = (const float*)d_in[4];
    const float* rk2 = (const float*)d_in[5];
    const float* b2  = (const float*)d_in[6];
    const float* wd  = (const float*)d_in[7];
    const float* bd  = (const float*)d_in[8];
    float* out = (float*)d_out;

    dim3 grid(512), block(1024);
    hipLaunchKernelGGL(gru_stack_kernel, grid, block, 0, stream,
                       x, k1, rk1, b1, k2, rk2, b2, wd, bd, out);
}